// Round 21
// baseline (14917.868 us; speedup 1.0000x reference)
//
#include <hip/hip_runtime.h>

// Farthest point sampling, B=32, N=32768, npoint=4096.
// R21 = R18 chassis with the reduce rebuilt for ONE barrier/step, zero
// atomics:
//  - wave butterfly carries (val,idx); 16 wave leaders PLAIN-write their
//    packed key (f32bits(dist)<<32 | ~idx) to s_slots[k&1][wv];
//  - ONE __syncthreads;
//  - every lane reads slot[lane&15] (4 lanes/slot -> same-addr broadcast,
//    conflict-free, single ds_read_b64 issue) and a 4-stage u64 shuffle
//    max gives ALL threads the winner; w = ~low32.
//  - double buffer by step parity: no resets, no rotation. WAR-safe: the
//    barrier of step k+1 orders all step-k slot reads before any step-k+2
//    write to the same buffer.
// First-occurrence argmax preserved: max key = max dist, ties -> max ~idx
// = min idx; per-thread ascending strict-> scan; wave butterfly ties ->
// smaller idx. (R18's proven semantics.)
// Inner loop / centroid-from-global-broadcast / bit-exact chain: R18.
// PASSING arithmetic (R6): d = fmaf(dz,dz, fmaf(dx,dx, dy*dy)),
// contract(off), fminf chain. Output float32: idx then coords.

#define BATCH  32
#define NPTS   32768
#define NPOINT 4096
#define NT     1024
#define NCH    16            // chunks of 2: 32 points per thread

__global__ __launch_bounds__(NT, 1)
__attribute__((amdgpu_num_vgpr(128)))
void fps_kernel(
    const float* __restrict__ xyz,   // [B, N, 3] float32
    float* __restrict__ out_idx,     // [B, NPOINT]
    float* __restrict__ out_xyz)     // [B, NPOINT, 3]
{
#pragma clang fp contract(off)
    __shared__ float pz_lds[NPTS];                 // 128 KB static
    __shared__ unsigned long long s_slots[2][16];  // double-buffered slots

    const int b   = blockIdx.x;
    const int tid = threadIdx.x;
    const float* base = xyz + (size_t)b * NPTS * 3;

    float px[NCH * 2], py[NCH * 2], dist[NCH * 2];
#pragma unroll
    for (int c = 0; c < NCH; ++c) {
#pragma unroll
        for (int j = 0; j < 2; ++j) {
            const int i = c * 2 + j;
            const int g = c * 2048 + 2 * tid + j;
            px[i] = base[g * 3 + 0];
            py[i] = base[g * 3 + 1];
            pz_lds[g] = base[g * 3 + 2];
            dist[i] = 1e10f;
        }
    }
    __syncthreads();                       // pz_lds ready

    int w = 1;   // RAN=False seed
    int p = 0;   // buffer parity k&1

    for (int k = 0; k < NPOINT; ++k) {
        // Broadcast centroid from global (same addr across lanes, L2-hot).
        const float cx = base[w * 3 + 0];
        const float cy = base[w * 3 + 1];
        const float cz = base[w * 3 + 2];
        if (tid == 0) {
            out_idx[(size_t)b * NPOINT + k] = (float)w;
            float* o = out_xyz + ((size_t)b * NPOINT + k) * 3;
            o[0] = cx; o[1] = cy; o[2] = cz;
        }
        if (k == NPOINT - 1) break;        // last output written; done

        // Distance update + first-occurrence argmax (ascending c,j order;
        // strict > keeps the first max — numpy semantics).
        float best = -1.0f;
        int   lc   = 63;
#pragma unroll
        for (int c = 0; c < NCH; ++c) {
            const float2 zz = *(const float2*)&pz_lds[c * 2048 + 2 * tid];
            const float pzv[2] = { zz.x, zz.y };
#pragma unroll
            for (int j = 0; j < 2; ++j) {
                const int i = c * 2 + j;
                const float dx = px[i] - cx;
                const float dy = py[i] - cy;
                const float dz = pzv[j] - cz;
                const float d  = fmaf(dz, dz, fmaf(dx, dx, dy * dy));
                const float nd = fminf(dist[i], d);
                dist[i] = nd;
                if (nd > best) { best = nd; lc = 2 * c + j; }
            }
        }
        int bi = (lc >> 1) * 2048 + 2 * tid + (lc & 1);

        // Wave (64-lane) butterfly argmax; ties -> smaller index.
#pragma unroll
        for (int off = 1; off < 64; off <<= 1) {
            const float ov = __shfl_xor(best, off, 64);
            const int   oi = __shfl_xor(bi,   off, 64);
            if (ov > best || (ov == best && oi < bi)) { best = ov; bi = oi; }
        }

        // Leaders plain-write packed key; ONE barrier; all lanes reduce.
        if ((tid & 63) == 0) {
            s_slots[p][tid >> 6] =
                ((unsigned long long)__float_as_uint(best) << 32) |
                (unsigned int)(~bi);
        }
        __syncthreads();                   // slots published (only barrier)

        unsigned long long kk = s_slots[p][tid & 15];  // 4 lanes/slot: bcast
#pragma unroll
        for (int off = 1; off < 16; off <<= 1) {
            const unsigned long long o = __shfl_xor(kk, off, 64);
            if (o > kk) kk = o;
        }
        w = (int)(~(unsigned int)kk);      // low word = ~idx
        p ^= 1;
    }
}

extern "C" void kernel_launch(void* const* d_in, const int* in_sizes, int n_in,
                              void* d_out, int out_size, void* d_ws, size_t ws_size,
                              hipStream_t stream) {
    const float* xyz = (const float*)d_in[0];
    float* out = (float*)d_out;
    float* out_idx = out;                              // B*NPOINT floats
    float* out_xyz = out + (size_t)BATCH * NPOINT;     // B*NPOINT*3 floats

    fps_kernel<<<BATCH, NT, 0, stream>>>(xyz, out_idx, out_xyz);
}

// Round 22
// 8756.280 us; speedup vs baseline: 1.7037x; 1.7037x over previous
//
#include <hip/hip_runtime.h>

// Farthest point sampling, B=32, N=32768, npoint=4096.
// R22 = R18 (proven 8.76ms) with ONE change: phase-A wave max uses DPP
// (VALU pipe, ~50cyc serial) instead of 6 __shfl_xor stages (ds_bpermute,
// ~720cyc serial latency exposed before B1). rocPRIM-standard wave64
// reduce: quad_perm[1,0,3,2], quad_perm[2,3,0,1], row_half_mirror,
// row_mirror, row_bcast15(row_mask 0xa), row_bcast31(row_mask 0xc);
// lane 63 holds the wave max and issues the 32-bit LDS atomicMax.
// Everything else byte-identical to R18:
//  - static 128KB LDS z, pair ds_read_b64, centroid via global broadcast;
//  - inner loop tracks (best, lc) with strict-> ascending scan;
//  - two-phase 3-slot rotating reduce: atomicMax(dist bits) -> B1 ->
//    candidates atomicMin(first-achieving global idx) -> B2 -> reset
//    slot (k+2)%3. Numpy first-occurrence argmax preserved.
// PASSING arithmetic (R6, bit-exact): d = fmaf(dz,dz, fmaf(dx,dx, dy*dy)),
// contract(off), fminf chain. Output float32: idx then coords.

#define BATCH  32
#define NPTS   32768
#define NPOINT 4096
#define NT     1024
#define NCH    16            // chunks of 2: 32 points per thread

__device__ __forceinline__ float wave_max_dpp(float v) {
    // old = v -> masked/invalid lanes keep v (fmax(v,v)=v). All lanes active.
    unsigned int u = __float_as_uint(v);
    u = __float_as_uint(fmaxf(__uint_as_float(u), __uint_as_float(
            __builtin_amdgcn_update_dpp(u, u, 0xB1, 0xf, 0xf, false))));
    u = __float_as_uint(fmaxf(__uint_as_float(u), __uint_as_float(
            __builtin_amdgcn_update_dpp(u, u, 0x4E, 0xf, 0xf, false))));
    u = __float_as_uint(fmaxf(__uint_as_float(u), __uint_as_float(
            __builtin_amdgcn_update_dpp(u, u, 0x141, 0xf, 0xf, false))));
    u = __float_as_uint(fmaxf(__uint_as_float(u), __uint_as_float(
            __builtin_amdgcn_update_dpp(u, u, 0x140, 0xf, 0xf, false))));
    u = __float_as_uint(fmaxf(__uint_as_float(u), __uint_as_float(
            __builtin_amdgcn_update_dpp(u, u, 0x142, 0xa, 0xf, false))));
    u = __float_as_uint(fmaxf(__uint_as_float(u), __uint_as_float(
            __builtin_amdgcn_update_dpp(u, u, 0x143, 0xc, 0xf, false))));
    return __uint_as_float(u);   // lane 63 = max of all 64 lanes
}

__global__ __launch_bounds__(NT, 1)
__attribute__((amdgpu_num_vgpr(128)))
void fps_kernel(
    const float* __restrict__ xyz,   // [B, N, 3] float32
    float* __restrict__ out_idx,     // [B, NPOINT]
    float* __restrict__ out_xyz)     // [B, NPOINT, 3]
{
#pragma clang fp contract(off)
    __shared__ float pz_lds[NPTS];               // 128 KB static
    __shared__ unsigned int s_val[3];            // dist bits (>=0, monotone)
    __shared__ int s_idx[3];                     // winning global index

    const int b   = blockIdx.x;
    const int tid = threadIdx.x;
    const float* base = xyz + (size_t)b * NPTS * 3;

    float px[NCH * 2], py[NCH * 2], dist[NCH * 2];
#pragma unroll
    for (int c = 0; c < NCH; ++c) {
#pragma unroll
        for (int j = 0; j < 2; ++j) {
            const int i = c * 2 + j;
            const int g = c * 2048 + 2 * tid + j;
            px[i] = base[g * 3 + 0];
            py[i] = base[g * 3 + 1];
            pz_lds[g] = base[g * 3 + 2];
            dist[i] = 1e10f;
        }
    }
    if (tid == 0) {
        s_val[0] = 0u; s_val[1] = 0u; s_val[2] = 0u;
        s_idx[0] = 0x7fffffff; s_idx[1] = 0x7fffffff; s_idx[2] = 0x7fffffff;
    }
    __syncthreads();                       // pz_lds + slots ready

    int w = 1;   // RAN=False seed
    int p = 0;   // rotating slot index k%3

    for (int k = 0; k < NPOINT; ++k) {
        // Broadcast centroid from global (same addr across lanes, L2-hot).
        const float cx = base[w * 3 + 0];
        const float cy = base[w * 3 + 1];
        const float cz = base[w * 3 + 2];
        if (tid == 0) {
            out_idx[(size_t)b * NPOINT + k] = (float)w;
            float* o = out_xyz + ((size_t)b * NPOINT + k) * 3;
            o[0] = cx; o[1] = cy; o[2] = cz;
        }

        // Distance update + per-thread first-occurrence argmax.
        float best = -1.0f;
        int   lc   = 63;
#pragma unroll
        for (int c = 0; c < NCH; ++c) {
            const float2 zz = *(const float2*)&pz_lds[c * 2048 + 2 * tid];
            const float pzv[2] = { zz.x, zz.y };
#pragma unroll
            for (int j = 0; j < 2; ++j) {
                const int i = c * 2 + j;
                const float dx = px[i] - cx;
                const float dy = py[i] - cy;
                const float dz = pzv[j] - cz;
                const float d  = fmaf(dz, dz, fmaf(dx, dx, dy * dy));
                const float nd = fminf(dist[i], d);
                dist[i] = nd;
                if (nd > best) { best = nd; lc = 2 * c + j; }
            }
        }

        // Phase A: value-only wave max via DPP; lane 63 publishes.
        const float m = wave_max_dpp(best);
        if ((tid & 63) == 63)
            atomicMax(&s_val[p], __float_as_uint(m));
        __syncthreads();                   // B1: block max known
        const float M = __uint_as_float(s_val[p]);

        // Phase B: candidates (best==M) publish first-achieving index.
        if (best == M) {
            const int bi = (lc >> 1) * 2048 + 2 * tid + (lc & 1);
            atomicMin(&s_idx[p], bi);
        }
        __syncthreads();                   // B2: winning index known
        w = s_idx[p];
        // Reset slot for step k+2 (barriers of step k+1 order this write
        // before that slot's next atomics; its readers finished at k-1).
        const int pn2 = (p >= 1) ? (p - 1) : 2;   // (k+2)%3
        if (tid == 0) { s_val[pn2] = 0u; s_idx[pn2] = 0x7fffffff; }
        p = (p == 2) ? 0 : (p + 1);
    }
}

extern "C" void kernel_launch(void* const* d_in, const int* in_sizes, int n_in,
                              void* d_out, int out_size, void* d_ws, size_t ws_size,
                              hipStream_t stream) {
    const float* xyz = (const float*)d_in[0];
    float* out = (float*)d_out;
    float* out_idx = out;                              // B*NPOINT floats
    float* out_xyz = out + (size_t)BATCH * NPOINT;     // B*NPOINT*3 floats

    fps_kernel<<<BATCH, NT, 0, stream>>>(xyz, out_idx, out_xyz);
}